// Round 11
// baseline (213.996 us; speedup 1.0000x reference)
//
#include <hip/hip_runtime.h>
#include <hip/hip_bf16.h>

namespace {
constexpr int GN   = 262144;   // 64^3 grid points
constexpr int CV   = 6;
constexpr int HI   = 256, WI = 256;
constexpr int MAXN = 2048;
constexpr int CBLK = 256;      // count/select blocks (1024 threads each)
constexpr int NSEG = 8;        // raster segments per tile
constexpr float NEARZ = 0.01f;
constexpr float FILLC = 0.45f;

// ---- workspace layout (bytes) ----
constexpr size_t OFF_CNT   = 0;                        // u8 [GN]
constexpr size_t OFF_BC8   = OFF_CNT + GN;             // int [CBLK][8] per-block level hist
constexpr size_t OFF_PAR   = OFF_BC8 + CBLK*8*4;       // f32 [MAXN*12]
constexpr size_t OFF_KEY   = OFF_PAR + MAXN*12*4;      // u64 [MAXN]
constexpr size_t OFF_SPAR  = OFF_KEY + MAXN*8;         // f32 [MAXN*12]
constexpr size_t OFF_PART  = OFF_SPAR + MAXN*12*4;     // f32x4 [256*NSEG][256]
constexpr size_t WS_NEED   = OFF_PART + (size_t)256*NSEG*256*16;
}

__device__ __forceinline__ float sigm_(float x){ return 1.0f/(1.0f+expf(-x)); }

// ---------------- Stage 1: inside-count + per-block level histogram (1024-thr blocks) -------
__global__ void __launch_bounds__(1024) k_count(
    const float* __restrict__ mask, const float* __restrict__ grid,
    const float* __restrict__ p3d, const float* __restrict__ angle,
    const float* __restrict__ Ks, const float* __restrict__ vms,
    unsigned char* __restrict__ cnt8, int* __restrict__ bc8)
{
  int t = threadIdx.x;
  int p = blockIdx.x*1024 + t;
  float a = angle[0];
  float ca = cosf(a), sa = sinf(a);
  float gx = grid[p*3+0], gy = grid[p*3+1], gz = grid[p*3+2];
  float pwx = ca*gx - sa*gy + p3d[0];
  float pwy = sa*gx + ca*gy + p3d[1];
  float pwz = gz + p3d[2];
  int count = 0;
  for (int c = 0; c < CV; ++c){
    const float* R = vms + c*16;
    float cxx = R[0]*pwx + R[1]*pwy + R[2]*pwz + R[3];
    float cyy = R[4]*pwx + R[5]*pwy + R[6]*pwz + R[7];
    float czz = R[8]*pwx + R[9]*pwy + R[10]*pwz + R[11];
    const float* K = Ks + c*9;
    float u = (K[0]*cxx + K[1]*cyy + K[2]*czz)/czz;
    float v = (K[3]*cxx + K[4]*cyy + K[5]*czz)/czz;
    bool inb = (u>=0.f)&&(u<(float)WI)&&(v>=0.f)&&(v<(float)HI)&&(czz>NEARZ);
    int ui = (int)fminf(fmaxf(rintf(u),0.f),(float)(WI-1));
    int vi = (int)fminf(fmaxf(rintf(v),0.f),(float)(HI-1));
    bool inside = inb && (mask[(c*HI+vi)*WI+ui] > 0.5f);
    count += inside ? 1 : 0;
  }
  cnt8[p] = (unsigned char)count;
  __shared__ int lh[8];
  if (t < 8) lh[t] = 0;
  __syncthreads();
  int L = 6 - count;
  unsigned long long msk[7];
  #pragma unroll
  for (int lv = 0; lv < 7; ++lv) msk[lv] = __ballot(L == lv);
  int lane = t & 63;
  if (lane < 7){
    int c = (int)__popcll(msk[lane]);
    if (c) atomicAdd(&lh[lane], c);
  }
  __syncthreads();
  if (t < 8) bc8[blockIdx.x*8 + t] = lh[t];
}

// Jacobi rotation on named scalars: pair (p,q); two untouched off-diag pairs; V columns p,q.
#define JROT(dp,dq,opq, okp1,okq1, okp2,okq2, vp0,vq0,vp1,vq1,vp2,vq2,vp3,vq3)  \
  { float apq_ = opq;                                                           \
    if (fabsf(apq_) > 1e-30f){                                                  \
      float th_ = (dq - dp)/(2.f*apq_);                                         \
      float tt_ = (th_>=0.f?1.f:-1.f)/(fabsf(th_)+sqrtf(th_*th_+1.f));          \
      float c_ = 1.f/sqrtf(tt_*tt_+1.f), s_ = tt_*c_;                           \
      dp -= tt_*apq_; dq += tt_*apq_; opq = 0.f;                                \
      float t1_=okp1, t2_=okq1; okp1 = c_*t1_ - s_*t2_; okq1 = s_*t1_ + c_*t2_; \
      t1_=okp2; t2_=okq2; okp2 = c_*t1_ - s_*t2_; okq2 = s_*t1_ + c_*t2_;       \
      t1_=vp0; t2_=vq0; vp0 = c_*t1_ - s_*t2_; vq0 = s_*t1_ + c_*t2_;           \
      t1_=vp1; t2_=vq1; vp1 = c_*t1_ - s_*t2_; vq1 = s_*t1_ + c_*t2_;           \
      t1_=vp2; t2_=vq2; vp2 = c_*t1_ - s_*t2_; vq2 = s_*t1_ + c_*t2_;           \
      t1_=vp3; t2_=vq3; vp3 = c_*t1_ - s_*t2_; vq3 = s_*t1_ + c_*t2_;           \
    } }

// ---------------- Stage 2: select (inlined histogram scan) + feats + MLP + params -----------
// 256 blocks x 1024 threads; selected threads run the heavy per-gaussian work in-place.
__global__ void __launch_bounds__(1024) k_select_mlp(
    const unsigned char* __restrict__ cnt8, const int* __restrict__ bc8,
    const float* __restrict__ mask, const float* __restrict__ img,
    const float* __restrict__ grid, const float* __restrict__ p3d,
    const float* __restrict__ angle, const float* __restrict__ Ks,
    const float* __restrict__ vms, const float* __restrict__ w1,
    const float* __restrict__ b1, const float* __restrict__ w2,
    const float* __restrict__ b2, const float* __restrict__ scp,
    const int* __restrict__ vnp, float* __restrict__ par,
    unsigned long long* __restrict__ keys)
{
  int t = threadIdx.x, blk = blockIdx.x;
  __shared__ int sc[7][CBLK];      // 7 KB scan array
  __shared__ float4 w1t[128];      // per j: w1[0..3][j]
  __shared__ float4 w2t[128*4];    // per j: 14 floats padded to 16
  __shared__ float  b1s[128];
  __shared__ float  b2s[16];
  if (t < CBLK){
    const int* row = bc8 + t*8;
    #pragma unroll
    for (int k = 0; k < 7; ++k) sc[k][t] = row[k];
  } else if (t < CBLK + 128){
    int j = t - CBLK;
    w1t[j] = make_float4(w1[j], w1[128+j], w1[256+j], w1[384+j]);
    b1s[j] = b1[j];
  } else if (t < CBLK + 128 + 16){
    int j = t - CBLK - 128;
    b2s[j] = (j < 14) ? b2[j] : 0.f;
  }
  if (t >= 512){
    float* w2f = (float*)w2t;
    int base = (t - 512)*4;
    #pragma unroll
    for (int q = 0; q < 4; ++q){
      int i = base + q; int j = i >> 4, c = i & 15;
      w2f[i] = (c < 14) ? w2[j*14+c] : 0.f;
    }
  }
  __syncthreads();
  // Hillis-Steele inclusive scan over 256 entries x 7 levels
  for (int ofs = 1; ofs < CBLK; ofs <<= 1){
    int x0 = 0, x1 = 0;
    int i0 = t & 255, L0 = t >> 8;
    int i1 = i0, L1 = L0 + 4;
    x0 = (i0 >= ofs) ? sc[L0][i0-ofs] : 0;
    if (L1 < 7) x1 = (i1 >= ofs) ? sc[L1][i1-ofs] : 0;
    __syncthreads();
    sc[L0][i0] += x0;
    if (L1 < 7) sc[L1][i1] += x1;
    __syncthreads();
  }
  __shared__ int pre[7], tot[7];
  if (t < 7){
    tot[t] = sc[t][CBLK-1];
    pre[t] = sc[t][blk] - bc8[blk*8 + t];
  }
  __syncthreads();
  int p = blk*1024 + t;
  int cnt = cnt8[p];
  int L = 6 - cnt;
  int lsL = 0;
  for (int l = 0; l < L; ++l) lsL += tot[l];
  unsigned long long msk[7];
  #pragma unroll
  for (int lv = 0; lv < 7; ++lv) msk[lv] = __ballot(L == lv);
  int lane = t & 63, wv = t >> 6;
  __shared__ int wcnt[16][7];
  if (lane < 7) wcnt[wv][lane] = (int)__popcll(msk[lane]);
  __syncthreads();
  int local = (int)__popcll(msk[L] & ((1ull<<lane)-1ull));
  for (int w = 0; w < wv; ++w) local += wcnt[w][L];
  int pos = lsL + pre[L] + local;
  if (pos >= MAXN) return;
  // ======== selected: full per-gaussian pipeline (R6 arithmetic order) ========
  float a = angle[0];
  float cA = cosf(a), sA = sinf(a);
  float gx = grid[p*3+0], gy = grid[p*3+1], gz = grid[p*3+2];
  float pwx = cA*gx - sA*gy + p3d[0];
  float pwy = sA*gx + cA*gy + p3d[1];
  float pwz = gz + p3d[2];
  float sr = 0.f, sg = 0.f, sb = 0.f;
  #pragma unroll
  for (int c = 0; c < CV; ++c){
    const float* R = vms + c*16;
    float cxx = R[0]*pwx + R[1]*pwy + R[2]*pwz + R[3];
    float cyy = R[4]*pwx + R[5]*pwy + R[6]*pwz + R[7];
    float czz = R[8]*pwx + R[9]*pwy + R[10]*pwz + R[11];
    const float* K = Ks + c*9;
    float u = (K[0]*cxx + K[1]*cyy + K[2]*czz)/czz;
    float v = (K[3]*cxx + K[4]*cyy + K[5]*czz)/czz;
    bool inb = (u>=0.f)&&(u<(float)WI)&&(v>=0.f)&&(v<(float)HI)&&(czz>NEARZ);
    int ui = (int)fminf(fmaxf(rintf(u),0.f),(float)(WI-1));
    int vi = (int)fminf(fmaxf(rintf(v),0.f),(float)(HI-1));
    bool inside = inb && (mask[(c*HI+vi)*WI+ui] > 0.5f);
    if (inside){
      const float* ip = img + ((size_t)(c*HI+vi)*WI+ui)*3;
      sr += ip[0]; sg += ip[1]; sb += ip[2];
    }
  }
  float f0 = 10.f*((float)cnt/6.f) - 5.f;
  float f1, f2, f3;
  if (cnt == 6){ f1 = sr/6.f; f2 = sg/6.f; f3 = sb/6.f; }
  else { f1 = FILLC; f2 = FILLC; f3 = FILLC; }
  float o0=b2s[0],o1=b2s[1],o2=b2s[2],o3=b2s[3],o4=b2s[4],o5=b2s[5],o6=b2s[6];
  float o7=b2s[7],o8=b2s[8],o9=b2s[9],o10=b2s[10],o11=b2s[11],o12=b2s[12],o13=b2s[13];
  #pragma unroll 4
  for (int j = 0; j < 128; ++j){
    float4 wv4 = w1t[j];
    float hj = b1s[j] + f0*wv4.x + f1*wv4.y + f2*wv4.z + f3*wv4.w;
    hj = fmaxf(hj, 0.f);
    float4 wa = w2t[j*4+0], wb = w2t[j*4+1], wc = w2t[j*4+2], wd = w2t[j*4+3];
    o0 += hj*wa.x;  o1 += hj*wa.y;  o2 += hj*wa.z;  o3 += hj*wa.w;
    o4 += hj*wb.x;  o5 += hj*wb.y;  o6 += hj*wb.z;  o7 += hj*wb.w;
    o8 += hj*wc.x;  o9 += hj*wc.y;  o10 += hj*wc.z; o11 += hj*wc.w;
    o12 += hj*wd.x; o13 += hj*wd.y;
  }
  float q0=o0, q1=o1, q2=o2, q3=o3;
  float nq = q0*q0+q1*q1+q2*q2+q3*q3;
  float M00,M01,M02,M10,M11,M12,M20,M21,M22;
  if (nq < 4.76837158e-07f){
    M00=1.f;M01=0.f;M02=0.f;M10=0.f;M11=1.f;M12=0.f;M20=0.f;M21=0.f;M22=1.f;
  } else {
    float s2 = 2.0f/nq;
    float e11=q1*q1*s2, e22=q2*q2*s2, e33=q3*q3*s2;
    float e12=q1*q2*s2, e13=q1*q3*s2, e23=q2*q3*s2;
    float e10=q1*q0*s2, e20=q2*q0*s2, e30=q3*q0*s2;
    M00=1.f-e22-e33; M01=e12-e30; M02=e13+e20;
    M10=e12-e30;     M11=1.f;     M12=e23-e10;
    M20=e13-e20;     M21=e23+e10; M22=1.f-e11-e22;
  }
  float r00 = cA*M00 - sA*M10, r01 = cA*M01 - sA*M11, r02 = cA*M02 - sA*M12;
  float r10 = sA*M00 + cA*M10, r11 = sA*M01 + cA*M11, r12 = sA*M02 + cA*M12;
  float r20 = M20, r21 = M21, r22 = M22;
  float d0=(r00-r11-r22)/3.f, d1=(r11-r00-r22)/3.f, d2=(r22-r00-r11)/3.f, d3=(r00+r11+r22)/3.f;
  float g01=(r01+r10)/3.f, g02=(r02+r20)/3.f, g03=(r21-r12)/3.f;
  float g12=(r12+r21)/3.f, g13=(r02-r20)/3.f, g23=(r10-r01)/3.f;
  float v00=1.f,v01=0.f,v02=0.f,v03=0.f;
  float v10=0.f,v11=1.f,v12=0.f,v13=0.f;
  float v20=0.f,v21=0.f,v22=1.f,v23=0.f;
  float v30=0.f,v31=0.f,v32=0.f,v33=1.f;
  for (int sweep = 0; sweep < 7; ++sweep){
    JROT(d0,d1,g01, g02,g12, g03,g13, v00,v01, v10,v11, v20,v21, v30,v31)
    JROT(d0,d2,g02, g01,g12, g03,g23, v00,v02, v10,v12, v20,v22, v30,v32)
    JROT(d0,d3,g03, g01,g13, g02,g23, v00,v03, v10,v13, v20,v23, v30,v33)
    JROT(d1,d2,g12, g01,g02, g13,g23, v01,v02, v11,v12, v21,v22, v31,v32)
    JROT(d1,d3,g13, g01,g03, g12,g23, v01,v03, v11,v13, v21,v23, v31,v33)
    JROT(d2,d3,g23, g02,g03, g12,g13, v02,v03, v12,v13, v22,v23, v32,v33)
  }
  float bv = d0, qw = v30, qx = v00, qy = v10, qz = v20;
  if (d1 > bv){ bv = d1; qw = v31; qx = v01; qy = v11; qz = v21; }
  if (d2 > bv){ bv = d2; qw = v32; qx = v02; qy = v12; qz = v22; }
  if (d3 > bv){ bv = d3; qw = v33; qx = v03; qy = v13; qz = v23; }
  float qlen = sqrtf(qw*qw+qx*qx+qy*qy+qz*qz) + 1e-12f;
  float w = qw/qlen, x = qx/qlen, y = qy/qlen, z = qz/qlen;
  float Rq00 = 1.f-2.f*(y*y+z*z), Rq01 = 2.f*(x*y - w*z), Rq02 = 2.f*(x*z + w*y);
  float Rq10 = 2.f*(x*y + w*z), Rq11 = 1.f-2.f*(x*x+z*z), Rq12 = 2.f*(y*z - w*x);
  float Rq20 = 2.f*(x*z - w*y), Rq21 = 2.f*(y*z + w*x), Rq22 = 1.f-2.f*(x*x+y*y);
  float spv = scp[0];
  float sc0 = expf(o4+spv), sc1 = expf(o5+spv), sc2 = expf(o6+spv);
  float va = sc0*sc0, vb = sc1*sc1, vc = sc2*sc2;
  float C300 = Rq00*Rq00*va + Rq01*Rq01*vb + Rq02*Rq02*vc;
  float C301 = Rq00*Rq10*va + Rq01*Rq11*vb + Rq02*Rq12*vc;
  float C302 = Rq00*Rq20*va + Rq01*Rq21*vb + Rq02*Rq22*vc;
  float C311 = Rq10*Rq10*va + Rq11*Rq11*vb + Rq12*Rq12*vc;
  float C312 = Rq10*Rq20*va + Rq11*Rq21*vb + Rq12*Rq22*vc;
  float C322 = Rq20*Rq20*va + Rq21*Rq21*vb + Rq22*Rq22*vc;
  const float TWOVOX = (float)(2.0*(0.18/64.0));
  float mlx = gx + TWOVOX*tanhf(o11);
  float mly = gy + TWOVOX*tanhf(o12);
  float mlz = gz + TWOVOX*tanhf(o13);
  float mx = cA*mlx - sA*mly + p3d[0];
  float my = sA*mlx + cA*mly + p3d[1];
  float mz = mlz + p3d[2];
  int vn = vnp[0];
  const float* vm = vms + vn*16;
  const float* Kc = Ks + vn*9;
  float xc = vm[0]*mx + vm[1]*my + vm[2]*mz + vm[3];
  float yc = vm[4]*mx + vm[5]*my + vm[6]*mz + vm[7];
  float zc = vm[8]*mx + vm[9]*my + vm[10]*mz + vm[11];
  float R0=vm[0], R1=vm[1], R2=vm[2], R4=vm[4], R5=vm[5], R6=vm[6], R8=vm[8], R9=vm[9], R10=vm[10];
  float T00 = R0*C300 + R1*C301 + R2*C302;
  float T01 = R0*C301 + R1*C311 + R2*C312;
  float T02 = R0*C302 + R1*C312 + R2*C322;
  float T10 = R4*C300 + R5*C301 + R6*C302;
  float T11 = R4*C301 + R5*C311 + R6*C312;
  float T12 = R4*C302 + R5*C312 + R6*C322;
  float T20 = R8*C300 + R9*C301 + R10*C302;
  float T21 = R8*C301 + R9*C311 + R10*C312;
  float T22 = R8*C302 + R9*C312 + R10*C322;
  float cc00 = T00*R0 + T01*R1 + T02*R2;
  float cc01 = T00*R4 + T01*R5 + T02*R6;
  float cc02 = T00*R8 + T01*R9 + T02*R10;
  float cc11 = T10*R4 + T11*R5 + T12*R6;
  float cc12 = T10*R8 + T11*R9 + T12*R10;
  float cc22 = T20*R8 + T21*R9 + T22*R10;
  float fx = Kc[0], fy = Kc[4], cxk = Kc[2], cyk = Kc[5];
  float rz = 1.f/zc;
  float jx0 = fx*rz, jx2 = -fx*xc*rz*rz;
  float jy1 = fy*rz, jy2 = -fy*yc*rz*rz;
  float c2_00 = jx0*jx0*cc00 + 2.f*jx0*jx2*cc02 + jx2*jx2*cc22;
  float c2_01 = jx0*jy1*cc01 + jx0*jy2*cc02 + jx2*jy1*cc12 + jx2*jy2*cc22;
  float c2_11 = jy1*jy1*cc11 + 2.f*jy1*jy2*cc12 + jy2*jy2*cc22;
  float a2 = c2_00 + 0.3f, b2v = c2_01, c2 = c2_11 + 0.3f;
  float det = a2*c2 - b2v*b2v;
  float dets = (det > 1e-12f) ? det : 1.f;
  float conA = c2/dets, conB = -b2v/dets, conC = a2/dets;
  float lam = 0.5f*(a2+c2) + sqrtf(fmaxf(0.25f*(a2-c2)*(a2-c2) + b2v*b2v, 1e-12f));
  float radius = ceilf(3.f*sqrtf(lam));
  float mux = fx*xc*rz + cxk, muy = fy*yc*rz + cyk;
  bool valid = (zc > NEARZ) && (det > 1e-12f) && (radius > 2.0f);
  float prob = sigm_(10.f*((float)cnt/6.f) - 5.f - 0.25f);
  float t01 = fminf(fmaxf((prob - 0.25f)/0.75f, 0.f), 1.f);
  float opac = sigm_(t01);
  float op = valid ? opac : 0.f;
  float colr = fminf(fmaxf(sigm_(o8), 0.f), 0.99f);
  float colg = fminf(fmaxf(sigm_(o9), 0.f), 0.99f);
  float colb = fminf(fmaxf(sigm_(o10), 0.f), 0.99f);
  float tln = (op > 0.f) ? logf(255.f*op) : 0.f;
  float rxp = sqrtf(fmaxf(2.f*tln*a2, 0.f)) + 1.0f;
  float ryp = sqrtf(fmaxf(2.f*tln*c2, 0.f)) + 1.0f;
  float4* pr4 = (float4*)(par + (size_t)pos*12);
  pr4[0] = make_float4(mux, muy, conA, conB);
  pr4[1] = make_float4(conC, op, colr, colg);
  pr4[2] = make_float4(colb, zc, valid ? rxp : -1e9f, valid ? ryp : -1e9f);
  unsigned int zb = __float_as_uint(zc);
  zb = (zb & 0x80000000u) ? ~zb : (zb | 0x80000000u);
  keys[pos] = ((unsigned long long)zb << 11) | (unsigned long long)pos;
}

// ---------------- Stage 3: full rank + scatter, one kernel (16 blocks x 1024) ----------------
__global__ void __launch_bounds__(1024) k_ranksort(const unsigned long long* __restrict__ keys,
                                                   const float* __restrict__ par,
                                                   float* __restrict__ spar)
{
  __shared__ unsigned long long kk[MAXN];   // 16 KB
  __shared__ int pc[8][128];
  __shared__ int rk[128];
  int t = threadIdx.x;
  kk[t] = keys[t]; kk[t+1024] = keys[t+1024];
  int iloc = t & 127, jseg = t >> 7;        // 8 j-segments of 256
  int i = blockIdx.x*128 + iloc;
  unsigned long long ki = keys[i];
  __syncthreads();
  int cnt = 0;
  const int j0 = jseg*256;
  #pragma unroll 8
  for (int n = 0; n < 256; ++n) cnt += (kk[j0+n] < ki) ? 1 : 0;
  pc[jseg][iloc] = cnt;
  __syncthreads();
  if (t < 128){
    int r = 0;
    #pragma unroll
    for (int sgi = 0; sgi < 8; ++sgi) r += pc[sgi][t];
    rk[t] = r;
  }
  __syncthreads();
  // scatter 128 rows x 3 float4 with 384 threads
  const float4* src4 = (const float4*)par;
  float4* dst4 = (float4*)spar;
  for (int idx = t; idx < 128*3; idx += 1024){
    int row = idx/3, q = idx - row*3;
    dst4[(size_t)rk[row]*3 + q] = src4[(size_t)(blockIdx.x*128 + row)*3 + q];
  }
}

// ---------------- Stage 4a: per-(tile,segment) partial raster ----------------
__global__ void __launch_bounds__(256) k_raster_part(const float* __restrict__ spar,
                                                     float4* __restrict__ part)
{
  int raw = blockIdx.x;
  int seg = raw & (NSEG-1);
  int tilep = raw >> 3;
  int tile = (tilep*97 + seg*31) & 255;     // permutation per seg for CU load balance
  int tx = tile & 15, ty = tile >> 4;
  int lx = threadIdx.x & 15, ly = threadIdx.x >> 4;
  float pxc = tx*16 + lx + 0.5f, pyc = ty*16 + ly + 0.5f;
  float tileX0 = tx*16 + 0.5f, tileX1 = tx*16 + 15.5f;
  float tileY0 = ty*16 + 0.5f, tileY1 = ty*16 + 15.5f;
  __shared__ float4 lpA[256];   // mux,muy,conA,conB
  __shared__ float4 lpB[256];   // conC,op,colr,colg
  __shared__ float  lpC[256];   // colb
  __shared__ int wbase[4];
  int lane = threadIdx.x & 63, wv = threadIdx.x >> 6;
  const float4* sp4 = (const float4*)spar;
  float4 v0 = sp4[(size_t)(seg*256 + threadIdx.x)*3 + 0];
  float4 v1 = sp4[(size_t)(seg*256 + threadIdx.x)*3 + 1];
  float4 v2 = sp4[(size_t)(seg*256 + threadIdx.x)*3 + 2];
  float mux = v0.x, muy = v0.y, op = v1.y, rx = v2.z, ry = v2.w;
  bool keep = (op > 0.f) &&
              (mux + rx >= tileX0) && (mux - rx <= tileX1) &&
              (muy + ry >= tileY0) && (muy - ry <= tileY1);
  unsigned long long m = __ballot(keep);
  if (lane == 0) wbase[wv] = (int)__popcll(m);
  __syncthreads();
  int base = 0, total = 0;
  #pragma unroll
  for (int w = 0; w < 4; ++w){ if (w < wv) base += wbase[w]; total += wbase[w]; }
  if (keep){
    int pos = base + (int)__popcll(m & ((1ull<<lane)-1ull));
    lpA[pos] = v0; lpB[pos] = v1; lpC[pos] = v2.x;
  }
  __syncthreads();
  float T = 1.f, rr = 0.f, gg = 0.f, bb = 0.f;
  for (int n = 0; n < total; ++n){
    float4 A = lpA[n], B = lpB[n];
    float dx = pxc - A.x, dy = pyc - A.y;
    float sig = 0.5f*(A.z*dx*dx + B.x*dy*dy) + A.w*dx*dy;
    float alpha = B.y*expf(-sig);
    if (sig >= 0.f && alpha >= 1.0f/255.0f){
      alpha = fminf(alpha, 0.999f);
      float wgt = alpha*T;
      rr += wgt*B.z; gg += wgt*B.w; bb += wgt*lpC[n];
      T *= (1.f - alpha);
    }
  }
  part[(size_t)(tile*NSEG + seg)*256 + threadIdx.x] = make_float4(rr, gg, bb, T);
}

// ---------------- Stage 4b: combine segment partials in z order ----------------
__global__ void __launch_bounds__(256) k_combine(const float4* __restrict__ part,
                                                 const float* __restrict__ bg,
                                                 float* __restrict__ outp)
{
  int tile = blockIdx.x;
  int t = threadIdx.x;
  int tx = tile & 15, ty = tile >> 4;
  int px = tx*16 + (t & 15), py = ty*16 + (t >> 4);
  float rr = 0.f, gg = 0.f, bb = 0.f, T = 1.f;
  #pragma unroll
  for (int seg = 0; seg < NSEG; ++seg){
    float4 v = part[(size_t)(tile*NSEG + seg)*256 + t];
    rr += T*v.x; gg += T*v.y; bb += T*v.z; T *= v.w;
  }
  int pix = py*WI + px;
  outp[pix*3+0] = fminf(fmaxf(rr + T*bg[0], 0.f), 1.f);
  outp[pix*3+1] = fminf(fmaxf(gg + T*bg[1], 0.f), 1.f);
  outp[pix*3+2] = fminf(fmaxf(bb + T*bg[2], 0.f), 1.f);
  outp[HI*WI*3 + pix] = 1.f - T;
}

// ---------------- Fallback monolithic raster (if ws too small for partials) --------------
__global__ void __launch_bounds__(256) k_raster_mono(const float* __restrict__ spar,
                                                     const float* __restrict__ bg,
                                                     float* __restrict__ outp)
{
  int tile = blockIdx.x;
  int tx = tile & 15, ty = tile >> 4;
  int lx = threadIdx.x & 15, ly = threadIdx.x >> 4;
  int px = tx*16 + lx, py = ty*16 + ly;
  float pxc = px + 0.5f, pyc = py + 0.5f;
  float tileX0 = tx*16 + 0.5f, tileX1 = tx*16 + 15.5f;
  float tileY0 = ty*16 + 0.5f, tileY1 = ty*16 + 15.5f;
  float T = 1.f, rr = 0.f, gg = 0.f, bb = 0.f;
  __shared__ float4 lpA[256];
  __shared__ float4 lpB[256];
  __shared__ float  lpC[256];
  __shared__ int wbase[4];
  int lane = threadIdx.x & 63, wv = threadIdx.x >> 6;
  const float4* sp4 = (const float4*)spar;
  for (int ch = 0; ch < MAXN; ch += 256){
    float4 v0 = sp4[(size_t)(ch + threadIdx.x)*3 + 0];
    float4 v1 = sp4[(size_t)(ch + threadIdx.x)*3 + 1];
    float4 v2 = sp4[(size_t)(ch + threadIdx.x)*3 + 2];
    float mux = v0.x, muy = v0.y, op = v1.y, rx = v2.z, ry = v2.w;
    bool keep = (op > 0.f) &&
                (mux + rx >= tileX0) && (mux - rx <= tileX1) &&
                (muy + ry >= tileY0) && (muy - ry <= tileY1);
    unsigned long long m = __ballot(keep);
    int wc = (int)__popcll(m);
    __syncthreads();
    if (lane == 0) wbase[wv] = wc;
    __syncthreads();
    int base = 0, total = 0;
    #pragma unroll
    for (int w = 0; w < 4; ++w){ if (w < wv) base += wbase[w]; total += wbase[w]; }
    if (keep){
      int pos = base + (int)__popcll(m & ((1ull<<lane)-1ull));
      lpA[pos] = v0; lpB[pos] = v1; lpC[pos] = v2.x;
    }
    __syncthreads();
    for (int n = 0; n < total; ++n){
      float4 A = lpA[n], B = lpB[n];
      float dx = pxc - A.x, dy = pyc - A.y;
      float sig = 0.5f*(A.z*dx*dx + B.x*dy*dy) + A.w*dx*dy;
      float alpha = B.y*expf(-sig);
      if (sig >= 0.f && alpha >= 1.0f/255.0f){
        alpha = fminf(alpha, 0.999f);
        float wgt = alpha*T;
        rr += wgt*B.z; gg += wgt*B.w; bb += wgt*lpC[n];
        T *= (1.f - alpha);
      }
    }
  }
  int pix = py*WI + px;
  outp[pix*3+0] = fminf(fmaxf(rr + T*bg[0], 0.f), 1.f);
  outp[pix*3+1] = fminf(fmaxf(gg + T*bg[1], 0.f), 1.f);
  outp[pix*3+2] = fminf(fmaxf(bb + T*bg[2], 0.f), 1.f);
  outp[HI*WI*3 + pix] = 1.f - T;
}

extern "C" void kernel_launch(void* const* d_in, const int* in_sizes, int n_in,
                              void* d_out, int out_size, void* d_ws, size_t ws_size,
                              hipStream_t stream)
{
  const float* mask  = (const float*)d_in[0];
  const float* img   = (const float*)d_in[1];
  const float* p3d   = (const float*)d_in[2];
  const float* angle = (const float*)d_in[3];
  const float* grid  = (const float*)d_in[4];
  const float* Ks    = (const float*)d_in[5];
  const float* vms   = (const float*)d_in[6];
  const float* w1    = (const float*)d_in[7];
  const float* b1    = (const float*)d_in[8];
  const float* w2    = (const float*)d_in[9];
  const float* b2    = (const float*)d_in[10];
  const float* scp   = (const float*)d_in[11];
  const float* bg    = (const float*)d_in[12];
  const int*   vn    = (const int*)d_in[13];
  float* outp = (float*)d_out;
  char* ws = (char*)d_ws;
  unsigned char* cnt8 = (unsigned char*)(ws + OFF_CNT);
  int* bc8   = (int*)(ws + OFF_BC8);
  float* par   = (float*)(ws + OFF_PAR);
  unsigned long long* keys = (unsigned long long*)(ws + OFF_KEY);
  float* spar  = (float*)(ws + OFF_SPAR);
  float4* part = (float4*)(ws + OFF_PART);

  k_count     <<<CBLK, 1024, 0, stream>>>(mask, grid, p3d, angle, Ks, vms, cnt8, bc8);
  k_select_mlp<<<CBLK, 1024, 0, stream>>>(cnt8, bc8, mask, img, grid, p3d, angle, Ks, vms,
                                          w1, b1, w2, b2, scp, vn, par, keys);
  k_ranksort  <<<MAXN/128, 1024, 0, stream>>>(keys, par, spar);
  if (ws_size >= WS_NEED){
    k_raster_part<<<256*NSEG, 256, 0, stream>>>(spar, part);
    k_combine    <<<256, 256, 0, stream>>>(part, bg, outp);
  } else {
    k_raster_mono<<<256, 256, 0, stream>>>(spar, bg, outp);
  }
}

// Round 12
// 213.993 us; speedup vs baseline: 1.0000x; 1.0000x over previous
//
#include <hip/hip_runtime.h>
#include <hip/hip_bf16.h>

namespace {
constexpr int GN   = 262144;   // 64^3 grid points
constexpr int CV   = 6;
constexpr int HI   = 256, WI = 256;
constexpr int MAXN = 2048;
constexpr int CBLK = 256;      // count/select blocks (1024 threads each)
constexpr int NSEG = 8;        // raster segments per tile
constexpr float NEARZ = 0.01f;
constexpr float FILLC = 0.45f;

// ---- workspace layout (bytes) ----
constexpr size_t OFF_CNT   = 0;                        // u8 [GN]
constexpr size_t OFF_BC8   = OFF_CNT + GN;             // int [CBLK][8] per-block level hist
constexpr size_t OFF_PAR   = OFF_BC8 + CBLK*8*4;       // f32 [MAXN*12]
constexpr size_t OFF_KEY   = OFF_PAR + MAXN*12*4;      // u64 [MAXN]
constexpr size_t OFF_SPAR  = OFF_KEY + MAXN*8;         // f32 [MAXN*12]
constexpr size_t OFF_PART  = OFF_SPAR + MAXN*12*4;     // f32x4 [256*NSEG][256]
constexpr size_t WS_NEED   = OFF_PART + (size_t)256*NSEG*256*16;
}

__device__ __forceinline__ float sigm_(float x){ return 1.0f/(1.0f+expf(-x)); }

// ---------------- Stage 1: inside-count + per-block level histogram (1024-thr blocks) -------
__global__ void __launch_bounds__(1024) k_count(
    const float* __restrict__ mask, const float* __restrict__ grid,
    const float* __restrict__ p3d, const float* __restrict__ angle,
    const float* __restrict__ Ks, const float* __restrict__ vms,
    unsigned char* __restrict__ cnt8, int* __restrict__ bc8)
{
  int t = threadIdx.x;
  int p = blockIdx.x*1024 + t;
  float a = angle[0];
  float ca = cosf(a), sa = sinf(a);
  float gx = grid[p*3+0], gy = grid[p*3+1], gz = grid[p*3+2];
  float pwx = ca*gx - sa*gy + p3d[0];
  float pwy = sa*gx + ca*gy + p3d[1];
  float pwz = gz + p3d[2];
  int count = 0;
  for (int c = 0; c < CV; ++c){
    const float* R = vms + c*16;
    float cxx = R[0]*pwx + R[1]*pwy + R[2]*pwz + R[3];
    float cyy = R[4]*pwx + R[5]*pwy + R[6]*pwz + R[7];
    float czz = R[8]*pwx + R[9]*pwy + R[10]*pwz + R[11];
    const float* K = Ks + c*9;
    float u = (K[0]*cxx + K[1]*cyy + K[2]*czz)/czz;
    float v = (K[3]*cxx + K[4]*cyy + K[5]*czz)/czz;
    bool inb = (u>=0.f)&&(u<(float)WI)&&(v>=0.f)&&(v<(float)HI)&&(czz>NEARZ);
    int ui = (int)fminf(fmaxf(rintf(u),0.f),(float)(WI-1));
    int vi = (int)fminf(fmaxf(rintf(v),0.f),(float)(HI-1));
    bool inside = inb && (mask[(c*HI+vi)*WI+ui] > 0.5f);
    count += inside ? 1 : 0;
  }
  cnt8[p] = (unsigned char)count;
  __shared__ int lh[8];
  if (t < 8) lh[t] = 0;
  __syncthreads();
  int L = 6 - count;
  unsigned long long msk[7];
  #pragma unroll
  for (int lv = 0; lv < 7; ++lv) msk[lv] = __ballot(L == lv);
  int lane = t & 63;
  if (lane < 7){
    int c = (int)__popcll(msk[lane]);
    if (c) atomicAdd(&lh[lane], c);
  }
  __syncthreads();
  if (t < 8) bc8[blockIdx.x*8 + t] = lh[t];
}

// Jacobi rotation on named scalars: pair (p,q); two untouched off-diag pairs; V columns p,q.
#define JROT(dp,dq,opq, okp1,okq1, okp2,okq2, vp0,vq0,vp1,vq1,vp2,vq2,vp3,vq3)  \
  { float apq_ = opq;                                                           \
    if (fabsf(apq_) > 1e-30f){                                                  \
      float th_ = (dq - dp)/(2.f*apq_);                                         \
      float tt_ = (th_>=0.f?1.f:-1.f)/(fabsf(th_)+sqrtf(th_*th_+1.f));          \
      float c_ = 1.f/sqrtf(tt_*tt_+1.f), s_ = tt_*c_;                           \
      dp -= tt_*apq_; dq += tt_*apq_; opq = 0.f;                                \
      float t1_=okp1, t2_=okq1; okp1 = c_*t1_ - s_*t2_; okq1 = s_*t1_ + c_*t2_; \
      t1_=okp2; t2_=okq2; okp2 = c_*t1_ - s_*t2_; okq2 = s_*t1_ + c_*t2_;       \
      t1_=vp0; t2_=vq0; vp0 = c_*t1_ - s_*t2_; vq0 = s_*t1_ + c_*t2_;           \
      t1_=vp1; t2_=vq1; vp1 = c_*t1_ - s_*t2_; vq1 = s_*t1_ + c_*t2_;           \
      t1_=vp2; t2_=vq2; vp2 = c_*t1_ - s_*t2_; vq2 = s_*t1_ + c_*t2_;           \
      t1_=vp3; t2_=vq3; vp3 = c_*t1_ - s_*t2_; vq3 = s_*t1_ + c_*t2_;           \
    } }

// ---------------- Stage 2: select (inlined histogram scan) + feats + MLP + params -----------
// 256 blocks x 1024 threads; (1024,4) => 1 block/CU, VGPR cap 128 — no spill in the epilogue.
__global__ void __launch_bounds__(1024, 4) k_select_mlp(
    const unsigned char* __restrict__ cnt8, const int* __restrict__ bc8,
    const float* __restrict__ mask, const float* __restrict__ img,
    const float* __restrict__ grid, const float* __restrict__ p3d,
    const float* __restrict__ angle, const float* __restrict__ Ks,
    const float* __restrict__ vms, const float* __restrict__ w1,
    const float* __restrict__ b1, const float* __restrict__ w2,
    const float* __restrict__ b2, const float* __restrict__ scp,
    const int* __restrict__ vnp, float* __restrict__ par,
    unsigned long long* __restrict__ keys)
{
  int t = threadIdx.x, blk = blockIdx.x;
  __shared__ int sc[7][CBLK];      // 7 KB scan array
  __shared__ float4 w1t[128];      // per j: w1[0..3][j]
  __shared__ float4 w2t[128*4];    // per j: 14 floats padded to 16
  __shared__ float  b1s[128];
  __shared__ float  b2s[16];
  if (t < CBLK){
    const int* row = bc8 + t*8;
    #pragma unroll
    for (int k = 0; k < 7; ++k) sc[k][t] = row[k];
  } else if (t < CBLK + 128){
    int j = t - CBLK;
    w1t[j] = make_float4(w1[j], w1[128+j], w1[256+j], w1[384+j]);
    b1s[j] = b1[j];
  } else if (t < CBLK + 128 + 16){
    int j = t - CBLK - 128;
    b2s[j] = (j < 14) ? b2[j] : 0.f;
  }
  if (t >= 512){
    float* w2f = (float*)w2t;
    int base = (t - 512)*4;
    #pragma unroll
    for (int q = 0; q < 4; ++q){
      int i = base + q; int j = i >> 4, c = i & 15;
      w2f[i] = (c < 14) ? w2[j*14+c] : 0.f;
    }
  }
  __syncthreads();
  // Hillis-Steele inclusive scan over 256 entries x 7 levels
  for (int ofs = 1; ofs < CBLK; ofs <<= 1){
    int x0 = 0, x1 = 0;
    int i0 = t & 255, L0 = t >> 8;
    int i1 = i0, L1 = L0 + 4;
    x0 = (i0 >= ofs) ? sc[L0][i0-ofs] : 0;
    if (L1 < 7) x1 = (i1 >= ofs) ? sc[L1][i1-ofs] : 0;
    __syncthreads();
    sc[L0][i0] += x0;
    if (L1 < 7) sc[L1][i1] += x1;
    __syncthreads();
  }
  __shared__ int pre[7], tot[7];
  if (t < 7){
    tot[t] = sc[t][CBLK-1];
    pre[t] = sc[t][blk] - bc8[blk*8 + t];
  }
  __syncthreads();
  int p = blk*1024 + t;
  int cnt = cnt8[p];
  int L = 6 - cnt;
  int lsL = 0;
  for (int l = 0; l < L; ++l) lsL += tot[l];
  unsigned long long msk[7];
  #pragma unroll
  for (int lv = 0; lv < 7; ++lv) msk[lv] = __ballot(L == lv);
  int lane = t & 63, wv = t >> 6;
  __shared__ int wcnt[16][7];
  if (lane < 7) wcnt[wv][lane] = (int)__popcll(msk[lane]);
  __syncthreads();
  int local = (int)__popcll(msk[L] & ((1ull<<lane)-1ull));
  for (int w = 0; w < wv; ++w) local += wcnt[w][L];
  int pos = lsL + pre[L] + local;
  if (pos >= MAXN) return;
  // ======== selected: full per-gaussian pipeline (R6 arithmetic order) ========
  float a = angle[0];
  float cA = cosf(a), sA = sinf(a);
  float gx = grid[p*3+0], gy = grid[p*3+1], gz = grid[p*3+2];
  float pwx = cA*gx - sA*gy + p3d[0];
  float pwy = sA*gx + cA*gy + p3d[1];
  float pwz = gz + p3d[2];
  float sr = 0.f, sg = 0.f, sb = 0.f;
  #pragma unroll
  for (int c = 0; c < CV; ++c){
    const float* R = vms + c*16;
    float cxx = R[0]*pwx + R[1]*pwy + R[2]*pwz + R[3];
    float cyy = R[4]*pwx + R[5]*pwy + R[6]*pwz + R[7];
    float czz = R[8]*pwx + R[9]*pwy + R[10]*pwz + R[11];
    const float* K = Ks + c*9;
    float u = (K[0]*cxx + K[1]*cyy + K[2]*czz)/czz;
    float v = (K[3]*cxx + K[4]*cyy + K[5]*czz)/czz;
    bool inb = (u>=0.f)&&(u<(float)WI)&&(v>=0.f)&&(v<(float)HI)&&(czz>NEARZ);
    int ui = (int)fminf(fmaxf(rintf(u),0.f),(float)(WI-1));
    int vi = (int)fminf(fmaxf(rintf(v),0.f),(float)(HI-1));
    bool inside = inb && (mask[(c*HI+vi)*WI+ui] > 0.5f);
    if (inside){
      const float* ip = img + ((size_t)(c*HI+vi)*WI+ui)*3;
      sr += ip[0]; sg += ip[1]; sb += ip[2];
    }
  }
  float f0 = 10.f*((float)cnt/6.f) - 5.f;
  float f1, f2, f3;
  if (cnt == 6){ f1 = sr/6.f; f2 = sg/6.f; f3 = sb/6.f; }
  else { f1 = FILLC; f2 = FILLC; f3 = FILLC; }
  float o0=b2s[0],o1=b2s[1],o2=b2s[2],o3=b2s[3],o4=b2s[4],o5=b2s[5],o6=b2s[6];
  float o7=b2s[7],o8=b2s[8],o9=b2s[9],o10=b2s[10],o11=b2s[11],o12=b2s[12],o13=b2s[13];
  #pragma unroll 4
  for (int j = 0; j < 128; ++j){
    float4 wv4 = w1t[j];
    float hj = b1s[j] + f0*wv4.x + f1*wv4.y + f2*wv4.z + f3*wv4.w;
    hj = fmaxf(hj, 0.f);
    float4 wa = w2t[j*4+0], wb = w2t[j*4+1], wc = w2t[j*4+2], wd = w2t[j*4+3];
    o0 += hj*wa.x;  o1 += hj*wa.y;  o2 += hj*wa.z;  o3 += hj*wa.w;
    o4 += hj*wb.x;  o5 += hj*wb.y;  o6 += hj*wb.z;  o7 += hj*wb.w;
    o8 += hj*wc.x;  o9 += hj*wc.y;  o10 += hj*wc.z; o11 += hj*wc.w;
    o12 += hj*wd.x; o13 += hj*wd.y;
  }
  float q0=o0, q1=o1, q2=o2, q3=o3;
  float nq = q0*q0+q1*q1+q2*q2+q3*q3;
  float M00,M01,M02,M10,M11,M12,M20,M21,M22;
  if (nq < 4.76837158e-07f){
    M00=1.f;M01=0.f;M02=0.f;M10=0.f;M11=1.f;M12=0.f;M20=0.f;M21=0.f;M22=1.f;
  } else {
    float s2 = 2.0f/nq;
    float e11=q1*q1*s2, e22=q2*q2*s2, e33=q3*q3*s2;
    float e12=q1*q2*s2, e13=q1*q3*s2, e23=q2*q3*s2;
    float e10=q1*q0*s2, e20=q2*q0*s2, e30=q3*q0*s2;
    M00=1.f-e22-e33; M01=e12-e30; M02=e13+e20;
    M10=e12-e30;     M11=1.f;     M12=e23-e10;
    M20=e13-e20;     M21=e23+e10; M22=1.f-e11-e22;
  }
  float r00 = cA*M00 - sA*M10, r01 = cA*M01 - sA*M11, r02 = cA*M02 - sA*M12;
  float r10 = sA*M00 + cA*M10, r11 = sA*M01 + cA*M11, r12 = sA*M02 + cA*M12;
  float r20 = M20, r21 = M21, r22 = M22;
  float d0=(r00-r11-r22)/3.f, d1=(r11-r00-r22)/3.f, d2=(r22-r00-r11)/3.f, d3=(r00+r11+r22)/3.f;
  float g01=(r01+r10)/3.f, g02=(r02+r20)/3.f, g03=(r21-r12)/3.f;
  float g12=(r12+r21)/3.f, g13=(r02-r20)/3.f, g23=(r10-r01)/3.f;
  float v00=1.f,v01=0.f,v02=0.f,v03=0.f;
  float v10=0.f,v11=1.f,v12=0.f,v13=0.f;
  float v20=0.f,v21=0.f,v22=1.f,v23=0.f;
  float v30=0.f,v31=0.f,v32=0.f,v33=1.f;
  for (int sweep = 0; sweep < 7; ++sweep){
    JROT(d0,d1,g01, g02,g12, g03,g13, v00,v01, v10,v11, v20,v21, v30,v31)
    JROT(d0,d2,g02, g01,g12, g03,g23, v00,v02, v10,v12, v20,v22, v30,v32)
    JROT(d0,d3,g03, g01,g13, g02,g23, v00,v03, v10,v13, v20,v23, v30,v33)
    JROT(d1,d2,g12, g01,g02, g13,g23, v01,v02, v11,v12, v21,v22, v31,v32)
    JROT(d1,d3,g13, g01,g03, g12,g23, v01,v03, v11,v13, v21,v23, v31,v33)
    JROT(d2,d3,g23, g02,g03, g12,g13, v02,v03, v12,v13, v22,v23, v32,v33)
  }
  float bv = d0, qw = v30, qx = v00, qy = v10, qz = v20;
  if (d1 > bv){ bv = d1; qw = v31; qx = v01; qy = v11; qz = v21; }
  if (d2 > bv){ bv = d2; qw = v32; qx = v02; qy = v12; qz = v22; }
  if (d3 > bv){ bv = d3; qw = v33; qx = v03; qy = v13; qz = v23; }
  float qlen = sqrtf(qw*qw+qx*qx+qy*qy+qz*qz) + 1e-12f;
  float w = qw/qlen, x = qx/qlen, y = qy/qlen, z = qz/qlen;
  float Rq00 = 1.f-2.f*(y*y+z*z), Rq01 = 2.f*(x*y - w*z), Rq02 = 2.f*(x*z + w*y);
  float Rq10 = 2.f*(x*y + w*z), Rq11 = 1.f-2.f*(x*x+z*z), Rq12 = 2.f*(y*z - w*x);
  float Rq20 = 2.f*(x*z - w*y), Rq21 = 2.f*(y*z + w*x), Rq22 = 1.f-2.f*(x*x+y*y);
  float spv = scp[0];
  float sc0 = expf(o4+spv), sc1 = expf(o5+spv), sc2 = expf(o6+spv);
  float va = sc0*sc0, vb = sc1*sc1, vc = sc2*sc2;
  float C300 = Rq00*Rq00*va + Rq01*Rq01*vb + Rq02*Rq02*vc;
  float C301 = Rq00*Rq10*va + Rq01*Rq11*vb + Rq02*Rq12*vc;
  float C302 = Rq00*Rq20*va + Rq01*Rq21*vb + Rq02*Rq22*vc;
  float C311 = Rq10*Rq10*va + Rq11*Rq11*vb + Rq12*Rq12*vc;
  float C312 = Rq10*Rq20*va + Rq11*Rq21*vb + Rq12*Rq22*vc;
  float C322 = Rq20*Rq20*va + Rq21*Rq21*vb + Rq22*Rq22*vc;
  const float TWOVOX = (float)(2.0*(0.18/64.0));
  float mlx = gx + TWOVOX*tanhf(o11);
  float mly = gy + TWOVOX*tanhf(o12);
  float mlz = gz + TWOVOX*tanhf(o13);
  float mx = cA*mlx - sA*mly + p3d[0];
  float my = sA*mlx + cA*mly + p3d[1];
  float mz = mlz + p3d[2];
  int vn = vnp[0];
  const float* vm = vms + vn*16;
  const float* Kc = Ks + vn*9;
  float xc = vm[0]*mx + vm[1]*my + vm[2]*mz + vm[3];
  float yc = vm[4]*mx + vm[5]*my + vm[6]*mz + vm[7];
  float zc = vm[8]*mx + vm[9]*my + vm[10]*mz + vm[11];
  float R0=vm[0], R1=vm[1], R2=vm[2], R4=vm[4], R5=vm[5], R6=vm[6], R8=vm[8], R9=vm[9], R10=vm[10];
  float T00 = R0*C300 + R1*C301 + R2*C302;
  float T01 = R0*C301 + R1*C311 + R2*C312;
  float T02 = R0*C302 + R1*C312 + R2*C322;
  float T10 = R4*C300 + R5*C301 + R6*C302;
  float T11 = R4*C301 + R5*C311 + R6*C312;
  float T12 = R4*C302 + R5*C312 + R6*C322;
  float T20 = R8*C300 + R9*C301 + R10*C302;
  float T21 = R8*C301 + R9*C311 + R10*C312;
  float T22 = R8*C302 + R9*C312 + R10*C322;
  float cc00 = T00*R0 + T01*R1 + T02*R2;
  float cc01 = T00*R4 + T01*R5 + T02*R6;
  float cc02 = T00*R8 + T01*R9 + T02*R10;
  float cc11 = T10*R4 + T11*R5 + T12*R6;
  float cc12 = T10*R8 + T11*R9 + T12*R10;
  float cc22 = T20*R8 + T21*R9 + T22*R10;
  float fx = Kc[0], fy = Kc[4], cxk = Kc[2], cyk = Kc[5];
  float rz = 1.f/zc;
  float jx0 = fx*rz, jx2 = -fx*xc*rz*rz;
  float jy1 = fy*rz, jy2 = -fy*yc*rz*rz;
  float c2_00 = jx0*jx0*cc00 + 2.f*jx0*jx2*cc02 + jx2*jx2*cc22;
  float c2_01 = jx0*jy1*cc01 + jx0*jy2*cc02 + jx2*jy1*cc12 + jx2*jy2*cc22;
  float c2_11 = jy1*jy1*cc11 + 2.f*jy1*jy2*cc12 + jy2*jy2*cc22;
  float a2 = c2_00 + 0.3f, b2v = c2_01, c2 = c2_11 + 0.3f;
  float det = a2*c2 - b2v*b2v;
  float dets = (det > 1e-12f) ? det : 1.f;
  float conA = c2/dets, conB = -b2v/dets, conC = a2/dets;
  float lam = 0.5f*(a2+c2) + sqrtf(fmaxf(0.25f*(a2-c2)*(a2-c2) + b2v*b2v, 1e-12f));
  float radius = ceilf(3.f*sqrtf(lam));
  float mux = fx*xc*rz + cxk, muy = fy*yc*rz + cyk;
  bool valid = (zc > NEARZ) && (det > 1e-12f) && (radius > 2.0f);
  float prob = sigm_(10.f*((float)cnt/6.f) - 5.f - 0.25f);
  float t01 = fminf(fmaxf((prob - 0.25f)/0.75f, 0.f), 1.f);
  float opac = sigm_(t01);
  float op = valid ? opac : 0.f;
  float colr = fminf(fmaxf(sigm_(o8), 0.f), 0.99f);
  float colg = fminf(fmaxf(sigm_(o9), 0.f), 0.99f);
  float colb = fminf(fmaxf(sigm_(o10), 0.f), 0.99f);
  float tln = (op > 0.f) ? logf(255.f*op) : 0.f;
  float rxp = sqrtf(fmaxf(2.f*tln*a2, 0.f)) + 1.0f;
  float ryp = sqrtf(fmaxf(2.f*tln*c2, 0.f)) + 1.0f;
  float4* pr4 = (float4*)(par + (size_t)pos*12);
  pr4[0] = make_float4(mux, muy, conA, conB);
  pr4[1] = make_float4(conC, op, colr, colg);
  pr4[2] = make_float4(colb, zc, valid ? rxp : -1e9f, valid ? ryp : -1e9f);
  unsigned int zb = __float_as_uint(zc);
  zb = (zb & 0x80000000u) ? ~zb : (zb | 0x80000000u);
  keys[pos] = ((unsigned long long)zb << 11) | (unsigned long long)pos;
}

// ---------------- Stage 3: full rank + scatter, one kernel (16 blocks x 1024) ----------------
__global__ void __launch_bounds__(1024) k_ranksort(const unsigned long long* __restrict__ keys,
                                                   const float* __restrict__ par,
                                                   float* __restrict__ spar)
{
  __shared__ unsigned long long kk[MAXN];   // 16 KB
  __shared__ int pc[8][128];
  __shared__ int rk[128];
  int t = threadIdx.x;
  kk[t] = keys[t]; kk[t+1024] = keys[t+1024];
  int iloc = t & 127, jseg = t >> 7;        // 8 j-segments of 256
  int i = blockIdx.x*128 + iloc;
  unsigned long long ki = keys[i];
  __syncthreads();
  int cnt = 0;
  const int j0 = jseg*256;
  #pragma unroll 8
  for (int n = 0; n < 256; ++n) cnt += (kk[j0+n] < ki) ? 1 : 0;
  pc[jseg][iloc] = cnt;
  __syncthreads();
  if (t < 128){
    int r = 0;
    #pragma unroll
    for (int sgi = 0; sgi < 8; ++sgi) r += pc[sgi][t];
    rk[t] = r;
  }
  __syncthreads();
  const float4* src4 = (const float4*)par;
  float4* dst4 = (float4*)spar;
  for (int idx = t; idx < 128*3; idx += 1024){
    int row = idx/3, q = idx - row*3;
    dst4[(size_t)rk[row]*3 + q] = src4[(size_t)(blockIdx.x*128 + row)*3 + q];
  }
}

// ---------------- Stage 4a: per-(tile,segment) partial raster ----------------
__global__ void __launch_bounds__(256) k_raster_part(const float* __restrict__ spar,
                                                     float4* __restrict__ part)
{
  int raw = blockIdx.x;
  int seg = raw & (NSEG-1);
  int tilep = raw >> 3;
  int tile = (tilep*97 + seg*31) & 255;     // permutation per seg for CU load balance
  int tx = tile & 15, ty = tile >> 4;
  int lx = threadIdx.x & 15, ly = threadIdx.x >> 4;
  float pxc = tx*16 + lx + 0.5f, pyc = ty*16 + ly + 0.5f;
  float tileX0 = tx*16 + 0.5f, tileX1 = tx*16 + 15.5f;
  float tileY0 = ty*16 + 0.5f, tileY1 = ty*16 + 15.5f;
  __shared__ float4 lpA[256];   // mux,muy,conA,conB
  __shared__ float4 lpB[256];   // conC,op,colr,colg
  __shared__ float  lpC[256];   // colb
  __shared__ int wbase[4];
  int lane = threadIdx.x & 63, wv = threadIdx.x >> 6;
  const float4* sp4 = (const float4*)spar;
  float4 v0 = sp4[(size_t)(seg*256 + threadIdx.x)*3 + 0];
  float4 v1 = sp4[(size_t)(seg*256 + threadIdx.x)*3 + 1];
  float4 v2 = sp4[(size_t)(seg*256 + threadIdx.x)*3 + 2];
  float mux = v0.x, muy = v0.y, op = v1.y, rx = v2.z, ry = v2.w;
  bool keep = (op > 0.f) &&
              (mux + rx >= tileX0) && (mux - rx <= tileX1) &&
              (muy + ry >= tileY0) && (muy - ry <= tileY1);
  unsigned long long m = __ballot(keep);
  if (lane == 0) wbase[wv] = (int)__popcll(m);
  __syncthreads();
  int base = 0, total = 0;
  #pragma unroll
  for (int w = 0; w < 4; ++w){ if (w < wv) base += wbase[w]; total += wbase[w]; }
  if (keep){
    int pos = base + (int)__popcll(m & ((1ull<<lane)-1ull));
    lpA[pos] = v0; lpB[pos] = v1; lpC[pos] = v2.x;
  }
  __syncthreads();
  float T = 1.f, rr = 0.f, gg = 0.f, bb = 0.f;
  for (int n = 0; n < total; ++n){
    float4 A = lpA[n], B = lpB[n];
    float dx = pxc - A.x, dy = pyc - A.y;
    float sig = 0.5f*(A.z*dx*dx + B.x*dy*dy) + A.w*dx*dy;
    float alpha = B.y*expf(-sig);
    if (sig >= 0.f && alpha >= 1.0f/255.0f){
      alpha = fminf(alpha, 0.999f);
      float wgt = alpha*T;
      rr += wgt*B.z; gg += wgt*B.w; bb += wgt*lpC[n];
      T *= (1.f - alpha);
    }
  }
  part[(size_t)(tile*NSEG + seg)*256 + threadIdx.x] = make_float4(rr, gg, bb, T);
}

// ---------------- Stage 4b: combine segment partials in z order ----------------
__global__ void __launch_bounds__(256) k_combine(const float4* __restrict__ part,
                                                 const float* __restrict__ bg,
                                                 float* __restrict__ outp)
{
  int tile = blockIdx.x;
  int t = threadIdx.x;
  int tx = tile & 15, ty = tile >> 4;
  int px = tx*16 + (t & 15), py = ty*16 + (t >> 4);
  float rr = 0.f, gg = 0.f, bb = 0.f, T = 1.f;
  #pragma unroll
  for (int seg = 0; seg < NSEG; ++seg){
    float4 v = part[(size_t)(tile*NSEG + seg)*256 + t];
    rr += T*v.x; gg += T*v.y; bb += T*v.z; T *= v.w;
  }
  int pix = py*WI + px;
  outp[pix*3+0] = fminf(fmaxf(rr + T*bg[0], 0.f), 1.f);
  outp[pix*3+1] = fminf(fmaxf(gg + T*bg[1], 0.f), 1.f);
  outp[pix*3+2] = fminf(fmaxf(bb + T*bg[2], 0.f), 1.f);
  outp[HI*WI*3 + pix] = 1.f - T;
}

// ---------------- Fallback monolithic raster (if ws too small for partials) --------------
__global__ void __launch_bounds__(256) k_raster_mono(const float* __restrict__ spar,
                                                     const float* __restrict__ bg,
                                                     float* __restrict__ outp)
{
  int tile = blockIdx.x;
  int tx = tile & 15, ty = tile >> 4;
  int lx = threadIdx.x & 15, ly = threadIdx.x >> 4;
  int px = tx*16 + lx, py = ty*16 + ly;
  float pxc = px + 0.5f, pyc = py + 0.5f;
  float tileX0 = tx*16 + 0.5f, tileX1 = tx*16 + 15.5f;
  float tileY0 = ty*16 + 0.5f, tileY1 = ty*16 + 15.5f;
  float T = 1.f, rr = 0.f, gg = 0.f, bb = 0.f;
  __shared__ float4 lpA[256];
  __shared__ float4 lpB[256];
  __shared__ float  lpC[256];
  __shared__ int wbase[4];
  int lane = threadIdx.x & 63, wv = threadIdx.x >> 6;
  const float4* sp4 = (const float4*)spar;
  for (int ch = 0; ch < MAXN; ch += 256){
    float4 v0 = sp4[(size_t)(ch + threadIdx.x)*3 + 0];
    float4 v1 = sp4[(size_t)(ch + threadIdx.x)*3 + 1];
    float4 v2 = sp4[(size_t)(ch + threadIdx.x)*3 + 2];
    float mux = v0.x, muy = v0.y, op = v1.y, rx = v2.z, ry = v2.w;
    bool keep = (op > 0.f) &&
                (mux + rx >= tileX0) && (mux - rx <= tileX1) &&
                (muy + ry >= tileY0) && (muy - ry <= tileY1);
    unsigned long long m = __ballot(keep);
    int wc = (int)__popcll(m);
    __syncthreads();
    if (lane == 0) wbase[wv] = wc;
    __syncthreads();
    int base = 0, total = 0;
    #pragma unroll
    for (int w = 0; w < 4; ++w){ if (w < wv) base += wbase[w]; total += wbase[w]; }
    if (keep){
      int pos = base + (int)__popcll(m & ((1ull<<lane)-1ull));
      lpA[pos] = v0; lpB[pos] = v1; lpC[pos] = v2.x;
    }
    __syncthreads();
    for (int n = 0; n < total; ++n){
      float4 A = lpA[n], B = lpB[n];
      float dx = pxc - A.x, dy = pyc - A.y;
      float sig = 0.5f*(A.z*dx*dx + B.x*dy*dy) + A.w*dx*dy;
      float alpha = B.y*expf(-sig);
      if (sig >= 0.f && alpha >= 1.0f/255.0f){
        alpha = fminf(alpha, 0.999f);
        float wgt = alpha*T;
        rr += wgt*B.z; gg += wgt*B.w; bb += wgt*lpC[n];
        T *= (1.f - alpha);
      }
    }
  }
  int pix = py*WI + px;
  outp[pix*3+0] = fminf(fmaxf(rr + T*bg[0], 0.f), 1.f);
  outp[pix*3+1] = fminf(fmaxf(gg + T*bg[1], 0.f), 1.f);
  outp[pix*3+2] = fminf(fmaxf(bb + T*bg[2], 0.f), 1.f);
  outp[HI*WI*3 + pix] = 1.f - T;
}

extern "C" void kernel_launch(void* const* d_in, const int* in_sizes, int n_in,
                              void* d_out, int out_size, void* d_ws, size_t ws_size,
                              hipStream_t stream)
{
  const float* mask  = (const float*)d_in[0];
  const float* img   = (const float*)d_in[1];
  const float* p3d   = (const float*)d_in[2];
  const float* angle = (const float*)d_in[3];
  const float* grid  = (const float*)d_in[4];
  const float* Ks    = (const float*)d_in[5];
  const float* vms   = (const float*)d_in[6];
  const float* w1    = (const float*)d_in[7];
  const float* b1    = (const float*)d_in[8];
  const float* w2    = (const float*)d_in[9];
  const float* b2    = (const float*)d_in[10];
  const float* scp   = (const float*)d_in[11];
  const float* bg    = (const float*)d_in[12];
  const int*   vn    = (const int*)d_in[13];
  float* outp = (float*)d_out;
  char* ws = (char*)d_ws;
  unsigned char* cnt8 = (unsigned char*)(ws + OFF_CNT);
  int* bc8   = (int*)(ws + OFF_BC8);
  float* par   = (float*)(ws + OFF_PAR);
  unsigned long long* keys = (unsigned long long*)(ws + OFF_KEY);
  float* spar  = (float*)(ws + OFF_SPAR);
  float4* part = (float4*)(ws + OFF_PART);

  k_count     <<<CBLK, 1024, 0, stream>>>(mask, grid, p3d, angle, Ks, vms, cnt8, bc8);
  k_select_mlp<<<CBLK, 1024, 0, stream>>>(cnt8, bc8, mask, img, grid, p3d, angle, Ks, vms,
                                          w1, b1, w2, b2, scp, vn, par, keys);
  k_ranksort  <<<MAXN/128, 1024, 0, stream>>>(keys, par, spar);
  if (ws_size >= WS_NEED){
    k_raster_part<<<256*NSEG, 256, 0, stream>>>(spar, part);
    k_combine    <<<256, 256, 0, stream>>>(part, bg, outp);
  } else {
    k_raster_mono<<<256, 256, 0, stream>>>(spar, bg, outp);
  }
}

// Round 13
// 155.147 us; speedup vs baseline: 1.3793x; 1.3793x over previous
//
#include <hip/hip_runtime.h>
#include <hip/hip_bf16.h>

namespace {
constexpr int GN   = 262144;   // 64^3 grid points
constexpr int CV   = 6;
constexpr int HI   = 256, WI = 256;
constexpr int MAXN = 2048;
constexpr int CBLK = 256;      // count/select blocks (1024 threads each)
constexpr int NSEG = 8;        // raster segments per tile
constexpr float NEARZ = 0.01f;
constexpr float FILLC = 0.45f;

// ---- workspace layout (bytes) ----
constexpr size_t OFF_CNT   = 0;                        // u8 [GN]
constexpr size_t OFF_BC8   = OFF_CNT + GN;             // int [CBLK][8] per-block level hist
constexpr size_t OFF_SEL   = OFF_BC8 + CBLK*8*4;       // int [MAXN]
constexpr size_t OFF_SCNT  = OFF_SEL + MAXN*4;         // int [MAXN]
constexpr size_t OFF_PAR   = OFF_SCNT + MAXN*4;        // f32 [MAXN*12]
constexpr size_t OFF_KEY   = OFF_PAR + MAXN*12*4;      // u64 [MAXN]
constexpr size_t OFF_SPAR  = OFF_KEY + MAXN*8;         // f32 [MAXN*12]
constexpr size_t OFF_PART  = OFF_SPAR + MAXN*12*4;     // f32x4 [256*NSEG][256]
constexpr size_t WS_NEED   = OFF_PART + (size_t)256*NSEG*256*16;
}

__device__ __forceinline__ float sigm_(float x){ return 1.0f/(1.0f+expf(-x)); }
__device__ __forceinline__ float wsum_(float v){
  v += __shfl_xor(v, 32, 64); v += __shfl_xor(v, 16, 64); v += __shfl_xor(v, 8, 64);
  v += __shfl_xor(v, 4, 64);  v += __shfl_xor(v, 2, 64);  v += __shfl_xor(v, 1, 64);
  return v;
}

// ---------------- Stage 1: inside-count + per-block level histogram (1024-thr blocks) -------
__global__ void __launch_bounds__(1024) k_count(
    const float* __restrict__ mask, const float* __restrict__ grid,
    const float* __restrict__ p3d, const float* __restrict__ angle,
    const float* __restrict__ Ks, const float* __restrict__ vms,
    unsigned char* __restrict__ cnt8, int* __restrict__ bc8)
{
  int t = threadIdx.x;
  int p = blockIdx.x*1024 + t;
  float a = angle[0];
  float ca = cosf(a), sa = sinf(a);
  float gx = grid[p*3+0], gy = grid[p*3+1], gz = grid[p*3+2];
  float pwx = ca*gx - sa*gy + p3d[0];
  float pwy = sa*gx + ca*gy + p3d[1];
  float pwz = gz + p3d[2];
  int count = 0;
  for (int c = 0; c < CV; ++c){
    const float* R = vms + c*16;
    float cxx = R[0]*pwx + R[1]*pwy + R[2]*pwz + R[3];
    float cyy = R[4]*pwx + R[5]*pwy + R[6]*pwz + R[7];
    float czz = R[8]*pwx + R[9]*pwy + R[10]*pwz + R[11];
    const float* K = Ks + c*9;
    float u = (K[0]*cxx + K[1]*cyy + K[2]*czz)/czz;
    float v = (K[3]*cxx + K[4]*cyy + K[5]*czz)/czz;
    bool inb = (u>=0.f)&&(u<(float)WI)&&(v>=0.f)&&(v<(float)HI)&&(czz>NEARZ);
    int ui = (int)fminf(fmaxf(rintf(u),0.f),(float)(WI-1));
    int vi = (int)fminf(fmaxf(rintf(v),0.f),(float)(HI-1));
    bool inside = inb && (mask[(c*HI+vi)*WI+ui] > 0.5f);
    count += inside ? 1 : 0;
  }
  cnt8[p] = (unsigned char)count;
  __shared__ int lh[8];
  if (t < 8) lh[t] = 0;
  __syncthreads();
  int L = 6 - count;
  unsigned long long msk[7];
  #pragma unroll
  for (int lv = 0; lv < 7; ++lv) msk[lv] = __ballot(L == lv);
  int lane = t & 63;
  if (lane < 7){
    int c = (int)__popcll(msk[lane]);
    if (c) atomicAdd(&lh[lane], c);
  }
  __syncthreads();
  if (t < 8) bc8[blockIdx.x*8 + t] = lh[t];
}

// ---------------- Stage 2: select with inlined LDS scan of the 256x7 histogram ----------
__global__ void __launch_bounds__(1024) k_select(const unsigned char* __restrict__ cnt8,
                                                 const int* __restrict__ bc8,
                                                 int* __restrict__ sel, int* __restrict__ scnt)
{
  int t = threadIdx.x, blk = blockIdx.x;
  __shared__ int sc[7][CBLK];    // 7 KB
  if (t < CBLK){
    const int* row = bc8 + t*8;
    #pragma unroll
    for (int k = 0; k < 7; ++k) sc[k][t] = row[k];
  }
  __syncthreads();
  for (int ofs = 1; ofs < CBLK; ofs <<= 1){
    int x0 = 0, x1 = 0;
    int i0 = t & 255, L0 = t >> 8;
    int i1 = i0, L1 = L0 + 4;
    x0 = (i0 >= ofs) ? sc[L0][i0-ofs] : 0;
    if (L1 < 7) x1 = (i1 >= ofs) ? sc[L1][i1-ofs] : 0;
    __syncthreads();
    sc[L0][i0] += x0;
    if (L1 < 7) sc[L1][i1] += x1;
    __syncthreads();
  }
  __shared__ int pre[7], tot[7];
  if (t < 7){
    tot[t] = sc[t][CBLK-1];
    pre[t] = sc[t][blk] - bc8[blk*8 + t];
  }
  __syncthreads();
  int p = blk*1024 + t;
  int cnt = cnt8[p];
  int L = 6 - cnt;
  int lsL = 0;
  for (int l = 0; l < L; ++l) lsL += tot[l];
  unsigned long long msk[7];
  #pragma unroll
  for (int lv = 0; lv < 7; ++lv) msk[lv] = __ballot(L == lv);
  int lane = t & 63, wv = t >> 6;
  __shared__ int wcnt[16][7];
  if (lane < 7) wcnt[wv][lane] = (int)__popcll(msk[lane]);
  __syncthreads();
  int local = (int)__popcll(msk[L] & ((1ull<<lane)-1ull));
  for (int w = 0; w < wv; ++w) local += wcnt[w][L];
  int pos = lsL + pre[L] + local;
  if (pos < MAXN){ sel[pos] = p; scnt[pos] = cnt; }
}

// Jacobi rotation on named scalars: pair (p,q); two untouched off-diag pairs; V columns p,q.
#define JROT(dp,dq,opq, okp1,okq1, okp2,okq2, vp0,vq0,vp1,vq1,vp2,vq2,vp3,vq3)  \
  { float apq_ = opq;                                                           \
    if (fabsf(apq_) > 1e-30f){                                                  \
      float th_ = (dq - dp)/(2.f*apq_);                                         \
      float tt_ = (th_>=0.f?1.f:-1.f)/(fabsf(th_)+sqrtf(th_*th_+1.f));          \
      float c_ = 1.f/sqrtf(tt_*tt_+1.f), s_ = tt_*c_;                           \
      dp -= tt_*apq_; dq += tt_*apq_; opq = 0.f;                                \
      float t1_=okp1, t2_=okq1; okp1 = c_*t1_ - s_*t2_; okq1 = s_*t1_ + c_*t2_; \
      t1_=okp2; t2_=okq2; okp2 = c_*t1_ - s_*t2_; okq2 = s_*t1_ + c_*t2_;       \
      t1_=vp0; t2_=vq0; vp0 = c_*t1_ - s_*t2_; vq0 = s_*t1_ + c_*t2_;           \
      t1_=vp1; t2_=vq1; vp1 = c_*t1_ - s_*t2_; vq1 = s_*t1_ + c_*t2_;           \
      t1_=vp2; t2_=vq2; vp2 = c_*t1_ - s_*t2_; vq2 = s_*t1_ + c_*t2_;           \
      t1_=vp3; t2_=vq3; vp3 = c_*t1_ - s_*t2_; vq3 = s_*t1_ + c_*t2_;           \
    } }

// ---------------- Stage 3: fused feats + MLP + splat params — ONE WAVE PER GAUSSIAN ---------
// 512 blocks x 256 threads = 2048 waves; epilogue runs wave-uniform on all lanes.
__global__ void __launch_bounds__(256) k_mlp_params(
    const float* __restrict__ mask, const float* __restrict__ img,
    const float* __restrict__ grid, const float* __restrict__ p3d,
    const float* __restrict__ angle, const float* __restrict__ Ks,
    const float* __restrict__ vms, const float* __restrict__ w1,
    const float* __restrict__ b1, const float* __restrict__ w2,
    const float* __restrict__ b2, const float* __restrict__ scp,
    const int* __restrict__ vnp, const int* __restrict__ sel,
    const int* __restrict__ scnt, float* __restrict__ par,
    unsigned long long* __restrict__ keys)
{
  int lane = threadIdx.x & 63, wvi = threadIdx.x >> 6;
  int s = blockIdx.x*4 + wvi;
  int p = sel[s];
  int cnt = scnt[s];
  float a = angle[0];
  float cA = cosf(a), sA = sinf(a);
  float gx = grid[p*3+0], gy = grid[p*3+1], gz = grid[p*3+2];
  // ---- features: lane c<6 handles view c ----
  float sr = 0.f, sg = 0.f, sb = 0.f;
  if (lane < 6){
    float pwx = cA*gx - sA*gy + p3d[0];
    float pwy = sA*gx + cA*gy + p3d[1];
    float pwz = gz + p3d[2];
    const float* R = vms + lane*16;
    float cxx = R[0]*pwx + R[1]*pwy + R[2]*pwz + R[3];
    float cyy = R[4]*pwx + R[5]*pwy + R[6]*pwz + R[7];
    float czz = R[8]*pwx + R[9]*pwy + R[10]*pwz + R[11];
    const float* K = Ks + lane*9;
    float u = (K[0]*cxx + K[1]*cyy + K[2]*czz)/czz;
    float v = (K[3]*cxx + K[4]*cyy + K[5]*czz)/czz;
    bool inb = (u>=0.f)&&(u<(float)WI)&&(v>=0.f)&&(v<(float)HI)&&(czz>NEARZ);
    int ui = (int)fminf(fmaxf(rintf(u),0.f),(float)(WI-1));
    int vi = (int)fminf(fmaxf(rintf(v),0.f),(float)(HI-1));
    bool inside = inb && (mask[(lane*HI+vi)*WI+ui] > 0.5f);
    if (inside){
      const float* ip = img + ((size_t)(lane*HI+vi)*WI+ui)*3;
      sr = ip[0]; sg = ip[1]; sb = ip[2];
    }
  }
  sr = wsum_(sr); sg = wsum_(sg); sb = wsum_(sb);
  float f0 = 10.f*((float)cnt/6.f) - 5.f;
  float f1, f2, f3;
  if (cnt == 6){ f1 = sr/6.f; f2 = sg/6.f; f3 = sb/6.f; }
  else { f1 = FILLC; f2 = FILLC; f3 = FILLC; }
  // ---- MLP: lane handles hidden units j=lane and j=lane+64; butterfly-reduce 14 outputs ----
  float o0=0.f,o1=0.f,o2=0.f,o3=0.f,o4=0.f,o5=0.f,o6=0.f;
  float o7=0.f,o8=0.f,o9=0.f,o10=0.f,o11=0.f,o12=0.f,o13=0.f;
  #pragma unroll
  for (int r = 0; r < 2; ++r){
    int j = lane + r*64;
    float hj = b1[j] + f0*w1[j] + f1*w1[128+j] + f2*w1[256+j] + f3*w1[384+j];
    hj = fmaxf(hj, 0.f);
    const float* w2r = w2 + j*14;
    o0 += hj*w2r[0];  o1 += hj*w2r[1];  o2 += hj*w2r[2];  o3 += hj*w2r[3];
    o4 += hj*w2r[4];  o5 += hj*w2r[5];  o6 += hj*w2r[6];  o7 += hj*w2r[7];
    o8 += hj*w2r[8];  o9 += hj*w2r[9];  o10 += hj*w2r[10]; o11 += hj*w2r[11];
    o12 += hj*w2r[12]; o13 += hj*w2r[13];
  }
  o0 = wsum_(o0) + b2[0];   o1 = wsum_(o1) + b2[1];   o2 = wsum_(o2) + b2[2];
  o3 = wsum_(o3) + b2[3];   o4 = wsum_(o4) + b2[4];   o5 = wsum_(o5) + b2[5];
  o6 = wsum_(o6) + b2[6];   o7 = wsum_(o7) + b2[7];   o8 = wsum_(o8) + b2[8];
  o9 = wsum_(o9) + b2[9];   o10 = wsum_(o10) + b2[10]; o11 = wsum_(o11) + b2[11];
  o12 = wsum_(o12) + b2[12]; o13 = wsum_(o13) + b2[13];
  // ---- epilogue: wave-uniform, all lanes compute redundantly ----
  float q0=o0, q1=o1, q2=o2, q3=o3;
  float nq = q0*q0+q1*q1+q2*q2+q3*q3;
  float M00,M01,M02,M10,M11,M12,M20,M21,M22;
  if (nq < 4.76837158e-07f){
    M00=1.f;M01=0.f;M02=0.f;M10=0.f;M11=1.f;M12=0.f;M20=0.f;M21=0.f;M22=1.f;
  } else {
    float s2 = 2.0f/nq;
    float e11=q1*q1*s2, e22=q2*q2*s2, e33=q3*q3*s2;
    float e12=q1*q2*s2, e13=q1*q3*s2, e23=q2*q3*s2;
    float e10=q1*q0*s2, e20=q2*q0*s2, e30=q3*q0*s2;
    M00=1.f-e22-e33; M01=e12-e30; M02=e13+e20;
    M10=e12-e30;     M11=1.f;     M12=e23-e10;
    M20=e13-e20;     M21=e23+e10; M22=1.f-e11-e22;
  }
  float r00 = cA*M00 - sA*M10, r01 = cA*M01 - sA*M11, r02 = cA*M02 - sA*M12;
  float r10 = sA*M00 + cA*M10, r11 = sA*M01 + cA*M11, r12 = sA*M02 + cA*M12;
  float r20 = M20, r21 = M21, r22 = M22;
  float d0=(r00-r11-r22)/3.f, d1=(r11-r00-r22)/3.f, d2=(r22-r00-r11)/3.f, d3=(r00+r11+r22)/3.f;
  float g01=(r01+r10)/3.f, g02=(r02+r20)/3.f, g03=(r21-r12)/3.f;
  float g12=(r12+r21)/3.f, g13=(r02-r20)/3.f, g23=(r10-r01)/3.f;
  float v00=1.f,v01=0.f,v02=0.f,v03=0.f;
  float v10=0.f,v11=1.f,v12=0.f,v13=0.f;
  float v20=0.f,v21=0.f,v22=1.f,v23=0.f;
  float v30=0.f,v31=0.f,v32=0.f,v33=1.f;
  for (int sweep = 0; sweep < 7; ++sweep){
    JROT(d0,d1,g01, g02,g12, g03,g13, v00,v01, v10,v11, v20,v21, v30,v31)
    JROT(d0,d2,g02, g01,g12, g03,g23, v00,v02, v10,v12, v20,v22, v30,v32)
    JROT(d0,d3,g03, g01,g13, g02,g23, v00,v03, v10,v13, v20,v23, v30,v33)
    JROT(d1,d2,g12, g01,g02, g13,g23, v01,v02, v11,v12, v21,v22, v31,v32)
    JROT(d1,d3,g13, g01,g03, g12,g23, v01,v03, v11,v13, v21,v23, v31,v33)
    JROT(d2,d3,g23, g02,g03, g12,g13, v02,v03, v12,v13, v22,v23, v32,v33)
  }
  float bv = d0, qw = v30, qx = v00, qy = v10, qz = v20;
  if (d1 > bv){ bv = d1; qw = v31; qx = v01; qy = v11; qz = v21; }
  if (d2 > bv){ bv = d2; qw = v32; qx = v02; qy = v12; qz = v22; }
  if (d3 > bv){ bv = d3; qw = v33; qx = v03; qy = v13; qz = v23; }
  float qlen = sqrtf(qw*qw+qx*qx+qy*qy+qz*qz) + 1e-12f;
  float w = qw/qlen, x = qx/qlen, y = qy/qlen, z = qz/qlen;
  float Rq00 = 1.f-2.f*(y*y+z*z), Rq01 = 2.f*(x*y - w*z), Rq02 = 2.f*(x*z + w*y);
  float Rq10 = 2.f*(x*y + w*z), Rq11 = 1.f-2.f*(x*x+z*z), Rq12 = 2.f*(y*z - w*x);
  float Rq20 = 2.f*(x*z - w*y), Rq21 = 2.f*(y*z + w*x), Rq22 = 1.f-2.f*(x*x+y*y);
  float spv = scp[0];
  float sc0 = expf(o4+spv), sc1 = expf(o5+spv), sc2 = expf(o6+spv);
  float va = sc0*sc0, vb = sc1*sc1, vc = sc2*sc2;
  float C300 = Rq00*Rq00*va + Rq01*Rq01*vb + Rq02*Rq02*vc;
  float C301 = Rq00*Rq10*va + Rq01*Rq11*vb + Rq02*Rq12*vc;
  float C302 = Rq00*Rq20*va + Rq01*Rq21*vb + Rq02*Rq22*vc;
  float C311 = Rq10*Rq10*va + Rq11*Rq11*vb + Rq12*Rq12*vc;
  float C312 = Rq10*Rq20*va + Rq11*Rq21*vb + Rq12*Rq22*vc;
  float C322 = Rq20*Rq20*va + Rq21*Rq21*vb + Rq22*Rq22*vc;
  const float TWOVOX = (float)(2.0*(0.18/64.0));
  float mlx = gx + TWOVOX*tanhf(o11);
  float mly = gy + TWOVOX*tanhf(o12);
  float mlz = gz + TWOVOX*tanhf(o13);
  float mx = cA*mlx - sA*mly + p3d[0];
  float my = sA*mlx + cA*mly + p3d[1];
  float mz = mlz + p3d[2];
  int vn = vnp[0];
  const float* vm = vms + vn*16;
  const float* Kc = Ks + vn*9;
  float xc = vm[0]*mx + vm[1]*my + vm[2]*mz + vm[3];
  float yc = vm[4]*mx + vm[5]*my + vm[6]*mz + vm[7];
  float zc = vm[8]*mx + vm[9]*my + vm[10]*mz + vm[11];
  float R0=vm[0], R1=vm[1], R2=vm[2], R4=vm[4], R5=vm[5], R6=vm[6], R8=vm[8], R9=vm[9], R10=vm[10];
  float T00 = R0*C300 + R1*C301 + R2*C302;
  float T01 = R0*C301 + R1*C311 + R2*C312;
  float T02 = R0*C302 + R1*C312 + R2*C322;
  float T10 = R4*C300 + R5*C301 + R6*C302;
  float T11 = R4*C301 + R5*C311 + R6*C312;
  float T12 = R4*C302 + R5*C312 + R6*C322;
  float T20 = R8*C300 + R9*C301 + R10*C302;
  float T21 = R8*C301 + R9*C311 + R10*C312;
  float T22 = R8*C302 + R9*C312 + R10*C322;
  float cc00 = T00*R0 + T01*R1 + T02*R2;
  float cc01 = T00*R4 + T01*R5 + T02*R6;
  float cc02 = T00*R8 + T01*R9 + T02*R10;
  float cc11 = T10*R4 + T11*R5 + T12*R6;
  float cc12 = T10*R8 + T11*R9 + T12*R10;
  float cc22 = T20*R8 + T21*R9 + T22*R10;
  float fx = Kc[0], fy = Kc[4], cxk = Kc[2], cyk = Kc[5];
  float rz = 1.f/zc;
  float jx0 = fx*rz, jx2 = -fx*xc*rz*rz;
  float jy1 = fy*rz, jy2 = -fy*yc*rz*rz;
  float c2_00 = jx0*jx0*cc00 + 2.f*jx0*jx2*cc02 + jx2*jx2*cc22;
  float c2_01 = jx0*jy1*cc01 + jx0*jy2*cc02 + jx2*jy1*cc12 + jx2*jy2*cc22;
  float c2_11 = jy1*jy1*cc11 + 2.f*jy1*jy2*cc12 + jy2*jy2*cc22;
  float a2 = c2_00 + 0.3f, b2v = c2_01, c2 = c2_11 + 0.3f;
  float det = a2*c2 - b2v*b2v;
  float dets = (det > 1e-12f) ? det : 1.f;
  float conA = c2/dets, conB = -b2v/dets, conC = a2/dets;
  float lam = 0.5f*(a2+c2) + sqrtf(fmaxf(0.25f*(a2-c2)*(a2-c2) + b2v*b2v, 1e-12f));
  float radius = ceilf(3.f*sqrtf(lam));
  float mux = fx*xc*rz + cxk, muy = fy*yc*rz + cyk;
  bool valid = (zc > NEARZ) && (det > 1e-12f) && (radius > 2.0f);
  float prob = sigm_(10.f*((float)cnt/6.f) - 5.f - 0.25f);
  float t01 = fminf(fmaxf((prob - 0.25f)/0.75f, 0.f), 1.f);
  float opac = sigm_(t01);
  float op = valid ? opac : 0.f;
  float colr = fminf(fmaxf(sigm_(o8), 0.f), 0.99f);
  float colg = fminf(fmaxf(sigm_(o9), 0.f), 0.99f);
  float colb = fminf(fmaxf(sigm_(o10), 0.f), 0.99f);
  float tln = (op > 0.f) ? logf(255.f*op) : 0.f;
  float rxp = sqrtf(fmaxf(2.f*tln*a2, 0.f)) + 1.0f;
  float ryp = sqrtf(fmaxf(2.f*tln*c2, 0.f)) + 1.0f;
  if (lane == 0){
    float4* pr4 = (float4*)(par + (size_t)s*12);
    pr4[0] = make_float4(mux, muy, conA, conB);
    pr4[1] = make_float4(conC, op, colr, colg);
    pr4[2] = make_float4(colb, zc, valid ? rxp : -1e9f, valid ? ryp : -1e9f);
    unsigned int zb = __float_as_uint(zc);
    zb = (zb & 0x80000000u) ? ~zb : (zb | 0x80000000u);
    keys[s] = ((unsigned long long)zb << 11) | (unsigned long long)s;
  }
}

// ---------------- Stage 4: full rank + scatter, one kernel (16 blocks x 1024) ----------------
__global__ void __launch_bounds__(1024) k_ranksort(const unsigned long long* __restrict__ keys,
                                                   const float* __restrict__ par,
                                                   float* __restrict__ spar)
{
  __shared__ unsigned long long kk[MAXN];   // 16 KB
  __shared__ int pc[8][128];
  __shared__ int rk[128];
  int t = threadIdx.x;
  kk[t] = keys[t]; kk[t+1024] = keys[t+1024];
  int iloc = t & 127, jseg = t >> 7;        // 8 j-segments of 256
  int i = blockIdx.x*128 + iloc;
  unsigned long long ki = keys[i];
  __syncthreads();
  int cnt = 0;
  const int j0 = jseg*256;
  #pragma unroll 8
  for (int n = 0; n < 256; ++n) cnt += (kk[j0+n] < ki) ? 1 : 0;
  pc[jseg][iloc] = cnt;
  __syncthreads();
  if (t < 128){
    int r = 0;
    #pragma unroll
    for (int sgi = 0; sgi < 8; ++sgi) r += pc[sgi][t];
    rk[t] = r;
  }
  __syncthreads();
  const float4* src4 = (const float4*)par;
  float4* dst4 = (float4*)spar;
  for (int idx = t; idx < 128*3; idx += 1024){
    int row = idx/3, q = idx - row*3;
    dst4[(size_t)rk[row]*3 + q] = src4[(size_t)(blockIdx.x*128 + row)*3 + q];
  }
}

// ---------------- Stage 5a: per-(tile,segment) partial raster ----------------
__global__ void __launch_bounds__(256) k_raster_part(const float* __restrict__ spar,
                                                     float4* __restrict__ part)
{
  int raw = blockIdx.x;
  int seg = raw & (NSEG-1);
  int tilep = raw >> 3;
  int tile = (tilep*97 + seg*31) & 255;     // permutation per seg for CU load balance
  int tx = tile & 15, ty = tile >> 4;
  int lx = threadIdx.x & 15, ly = threadIdx.x >> 4;
  float pxc = tx*16 + lx + 0.5f, pyc = ty*16 + ly + 0.5f;
  float tileX0 = tx*16 + 0.5f, tileX1 = tx*16 + 15.5f;
  float tileY0 = ty*16 + 0.5f, tileY1 = ty*16 + 15.5f;
  __shared__ float4 lpA[256];   // mux,muy,conA,conB
  __shared__ float4 lpB[256];   // conC,op,colr,colg
  __shared__ float  lpC[256];   // colb
  __shared__ int wbase[4];
  int lane = threadIdx.x & 63, wv = threadIdx.x >> 6;
  const float4* sp4 = (const float4*)spar;
  float4 v0 = sp4[(size_t)(seg*256 + threadIdx.x)*3 + 0];
  float4 v1 = sp4[(size_t)(seg*256 + threadIdx.x)*3 + 1];
  float4 v2 = sp4[(size_t)(seg*256 + threadIdx.x)*3 + 2];
  float mux = v0.x, muy = v0.y, op = v1.y, rx = v2.z, ry = v2.w;
  bool keep = (op > 0.f) &&
              (mux + rx >= tileX0) && (mux - rx <= tileX1) &&
              (muy + ry >= tileY0) && (muy - ry <= tileY1);
  unsigned long long m = __ballot(keep);
  if (lane == 0) wbase[wv] = (int)__popcll(m);
  __syncthreads();
  int base = 0, total = 0;
  #pragma unroll
  for (int w = 0; w < 4; ++w){ if (w < wv) base += wbase[w]; total += wbase[w]; }
  if (keep){
    int pos = base + (int)__popcll(m & ((1ull<<lane)-1ull));
    lpA[pos] = v0; lpB[pos] = v1; lpC[pos] = v2.x;
  }
  __syncthreads();
  float T = 1.f, rr = 0.f, gg = 0.f, bb = 0.f;
  for (int n = 0; n < total; ++n){
    float4 A = lpA[n], B = lpB[n];
    float dx = pxc - A.x, dy = pyc - A.y;
    float sig = 0.5f*(A.z*dx*dx + B.x*dy*dy) + A.w*dx*dy;
    float alpha = B.y*expf(-sig);
    if (sig >= 0.f && alpha >= 1.0f/255.0f){
      alpha = fminf(alpha, 0.999f);
      float wgt = alpha*T;
      rr += wgt*B.z; gg += wgt*B.w; bb += wgt*lpC[n];
      T *= (1.f - alpha);
    }
  }
  part[(size_t)(tile*NSEG + seg)*256 + threadIdx.x] = make_float4(rr, gg, bb, T);
}

// ---------------- Stage 5b: combine segment partials in z order ----------------
__global__ void __launch_bounds__(256) k_combine(const float4* __restrict__ part,
                                                 const float* __restrict__ bg,
                                                 float* __restrict__ outp)
{
  int tile = blockIdx.x;
  int t = threadIdx.x;
  int tx = tile & 15, ty = tile >> 4;
  int px = tx*16 + (t & 15), py = ty*16 + (t >> 4);
  float rr = 0.f, gg = 0.f, bb = 0.f, T = 1.f;
  #pragma unroll
  for (int seg = 0; seg < NSEG; ++seg){
    float4 v = part[(size_t)(tile*NSEG + seg)*256 + t];
    rr += T*v.x; gg += T*v.y; bb += T*v.z; T *= v.w;
  }
  int pix = py*WI + px;
  outp[pix*3+0] = fminf(fmaxf(rr + T*bg[0], 0.f), 1.f);
  outp[pix*3+1] = fminf(fmaxf(gg + T*bg[1], 0.f), 1.f);
  outp[pix*3+2] = fminf(fmaxf(bb + T*bg[2], 0.f), 1.f);
  outp[HI*WI*3 + pix] = 1.f - T;
}

// ---------------- Fallback monolithic raster (if ws too small for partials) --------------
__global__ void __launch_bounds__(256) k_raster_mono(const float* __restrict__ spar,
                                                     const float* __restrict__ bg,
                                                     float* __restrict__ outp)
{
  int tile = blockIdx.x;
  int tx = tile & 15, ty = tile >> 4;
  int lx = threadIdx.x & 15, ly = threadIdx.x >> 4;
  int px = tx*16 + lx, py = ty*16 + ly;
  float pxc = px + 0.5f, pyc = py + 0.5f;
  float tileX0 = tx*16 + 0.5f, tileX1 = tx*16 + 15.5f;
  float tileY0 = ty*16 + 0.5f, tileY1 = ty*16 + 15.5f;
  float T = 1.f, rr = 0.f, gg = 0.f, bb = 0.f;
  __shared__ float4 lpA[256];
  __shared__ float4 lpB[256];
  __shared__ float  lpC[256];
  __shared__ int wbase[4];
  int lane = threadIdx.x & 63, wv = threadIdx.x >> 6;
  const float4* sp4 = (const float4*)spar;
  for (int ch = 0; ch < MAXN; ch += 256){
    float4 v0 = sp4[(size_t)(ch + threadIdx.x)*3 + 0];
    float4 v1 = sp4[(size_t)(ch + threadIdx.x)*3 + 1];
    float4 v2 = sp4[(size_t)(ch + threadIdx.x)*3 + 2];
    float mux = v0.x, muy = v0.y, op = v1.y, rx = v2.z, ry = v2.w;
    bool keep = (op > 0.f) &&
                (mux + rx >= tileX0) && (mux - rx <= tileX1) &&
                (muy + ry >= tileY0) && (muy - ry <= tileY1);
    unsigned long long m = __ballot(keep);
    int wc = (int)__popcll(m);
    __syncthreads();
    if (lane == 0) wbase[wv] = wc;
    __syncthreads();
    int base = 0, total = 0;
    #pragma unroll
    for (int w = 0; w < 4; ++w){ if (w < wv) base += wbase[w]; total += wbase[w]; }
    if (keep){
      int pos = base + (int)__popcll(m & ((1ull<<lane)-1ull));
      lpA[pos] = v0; lpB[pos] = v1; lpC[pos] = v2.x;
    }
    __syncthreads();
    for (int n = 0; n < total; ++n){
      float4 A = lpA[n], B = lpB[n];
      float dx = pxc - A.x, dy = pyc - A.y;
      float sig = 0.5f*(A.z*dx*dx + B.x*dy*dy) + A.w*dx*dy;
      float alpha = B.y*expf(-sig);
      if (sig >= 0.f && alpha >= 1.0f/255.0f){
        alpha = fminf(alpha, 0.999f);
        float wgt = alpha*T;
        rr += wgt*B.z; gg += wgt*B.w; bb += wgt*lpC[n];
        T *= (1.f - alpha);
      }
    }
  }
  int pix = py*WI + px;
  outp[pix*3+0] = fminf(fmaxf(rr + T*bg[0], 0.f), 1.f);
  outp[pix*3+1] = fminf(fmaxf(gg + T*bg[1], 0.f), 1.f);
  outp[pix*3+2] = fminf(fmaxf(bb + T*bg[2], 0.f), 1.f);
  outp[HI*WI*3 + pix] = 1.f - T;
}

extern "C" void kernel_launch(void* const* d_in, const int* in_sizes, int n_in,
                              void* d_out, int out_size, void* d_ws, size_t ws_size,
                              hipStream_t stream)
{
  const float* mask  = (const float*)d_in[0];
  const float* img   = (const float*)d_in[1];
  const float* p3d   = (const float*)d_in[2];
  const float* angle = (const float*)d_in[3];
  const float* grid  = (const float*)d_in[4];
  const float* Ks    = (const float*)d_in[5];
  const float* vms   = (const float*)d_in[6];
  const float* w1    = (const float*)d_in[7];
  const float* b1    = (const float*)d_in[8];
  const float* w2    = (const float*)d_in[9];
  const float* b2    = (const float*)d_in[10];
  const float* scp   = (const float*)d_in[11];
  const float* bg    = (const float*)d_in[12];
  const int*   vn    = (const int*)d_in[13];
  float* outp = (float*)d_out;
  char* ws = (char*)d_ws;
  unsigned char* cnt8 = (unsigned char*)(ws + OFF_CNT);
  int* bc8   = (int*)(ws + OFF_BC8);
  int* sel   = (int*)(ws + OFF_SEL);
  int* scnt  = (int*)(ws + OFF_SCNT);
  float* par   = (float*)(ws + OFF_PAR);
  unsigned long long* keys = (unsigned long long*)(ws + OFF_KEY);
  float* spar  = (float*)(ws + OFF_SPAR);
  float4* part = (float4*)(ws + OFF_PART);

  k_count     <<<CBLK, 1024, 0, stream>>>(mask, grid, p3d, angle, Ks, vms, cnt8, bc8);
  k_select    <<<CBLK, 1024, 0, stream>>>(cnt8, bc8, sel, scnt);
  k_mlp_params<<<MAXN/4, 256, 0, stream>>>(mask, img, grid, p3d, angle, Ks, vms,
                                           w1, b1, w2, b2, scp, vn, sel, scnt, par, keys);
  k_ranksort  <<<MAXN/128, 1024, 0, stream>>>(keys, par, spar);
  if (ws_size >= WS_NEED){
    k_raster_part<<<256*NSEG, 256, 0, stream>>>(spar, part);
    k_combine    <<<256, 256, 0, stream>>>(part, bg, outp);
  } else {
    k_raster_mono<<<256, 256, 0, stream>>>(spar, bg, outp);
  }
}